// Round 14
// baseline (460.419 us; speedup 1.0000x reference)
//
#include <hip/hip_runtime.h>
#include <hip/hip_fp16.h>

#define NN 100000
#define NE 1200000
#define DIN 128
#define DH 64
#define DOUT_FINAL 47
#define NPB 4        // nodes per block in gather kernels
#define MT 128       // GEMM m-tile
#define NBKT 391     // (NN + 255) >> 8  — bucket = dst >> 8 (256 nodes/bucket)
#define EB 4096      // edges per block in scatter_pairs_k

// ---------------- binned CSR build ----------------

// Phase A: global bucket histogram (LDS-privatized)
__global__ void bucket_hist_k(const int* __restrict__ dst, int* __restrict__ bktCnt) {
    __shared__ int h[NBKT];
    int tid = threadIdx.x;
    for (int i = tid; i < NBKT; i += 256) h[i] = 0;
    __syncthreads();
    for (int e = blockIdx.x * 256 + tid; e < NE; e += gridDim.x * 256)
        atomicAdd(&h[dst[e] >> 8], 1);
    __syncthreads();
    for (int i = tid; i < NBKT; i += 256)
        if (h[i]) atomicAdd(&bktCnt[i], h[i]);
}

// Phase A2: exclusive scan of bucket counts (single block)
__global__ void bscan_k(const int* __restrict__ bktCnt, int* __restrict__ bktPtr) {
    __shared__ int s[512];
    int tid = threadIdx.x;
    int v = (tid < NBKT) ? bktCnt[tid] : 0;
    s[tid] = v;
    __syncthreads();
    for (int off = 1; off < 512; off <<= 1) {
        int t = (tid >= off) ? s[tid - off] : 0;
        __syncthreads();
        s[tid] += t;
        __syncthreads();
    }
    if (tid < NBKT) bktPtr[tid] = s[tid] - v;
    if (tid == 0) bktPtr[NBKT] = NE;
}

// Phase B: scatter (src,dst) pairs into bucket-contiguous order.
__global__ void scatter_pairs_k(const int* __restrict__ src, const int* __restrict__ dst,
                                const int* __restrict__ bktPtr, int* __restrict__ bktCur,
                                int2* __restrict__ pairs) {
    __shared__ int h[NBKT];
    __shared__ int base[NBKT];
    __shared__ int cur[NBKT];
    int tid = threadIdx.x;
    int e0 = blockIdx.x * EB;
    int e1 = e0 + EB < NE ? e0 + EB : NE;
    for (int i = tid; i < NBKT; i += 256) { h[i] = 0; cur[i] = 0; }
    __syncthreads();
    for (int e = e0 + tid; e < e1; e += 256)
        atomicAdd(&h[dst[e] >> 8], 1);
    __syncthreads();
    for (int i = tid; i < NBKT; i += 256) {
        int c = h[i];
        base[i] = bktPtr[i] + (c ? atomicAdd(&bktCur[i], c) : 0);
    }
    __syncthreads();
    for (int e = e0 + tid; e < e1; e += 256) {
        int d = dst[e];
        int b = d >> 8;
        int p = base[b] + atomicAdd(&cur[b], 1);
        pairs[p] = make_int2(src[e], d);
    }
}

// Phase C: per-node degree via LDS-only atomics (one block per bucket)
__global__ void count_node_k(const int2* __restrict__ pairs, const int* __restrict__ bktPtr,
                             int* __restrict__ cnt) {
    __shared__ int h[256];
    int tid = threadIdx.x;
    int b = blockIdx.x;
    h[tid] = 0;
    __syncthreads();
    int e1 = bktPtr[b + 1];
    for (int e = bktPtr[b] + tid; e < e1; e += 256)
        atomicAdd(&h[pairs[e].y & 255], 1);
    __syncthreads();
    int node = (b << 8) + tid;
    if (node < NN) cnt[node] = h[tid];
}

// node-level exclusive scan (3 kernels)
__global__ void scan1_k(const int* __restrict__ cnt, int* __restrict__ ptr,
                        int* __restrict__ bsum, float* __restrict__ dinv) {
    __shared__ int s[256];
    int tid = threadIdx.x;
    int i = blockIdx.x * 256 + tid;
    int v = (i < NN) ? cnt[i] : 0;
    s[tid] = v;
    __syncthreads();
    for (int off = 1; off < 256; off <<= 1) {
        int t = (tid >= off) ? s[tid - off] : 0;
        __syncthreads();
        s[tid] += t;
        __syncthreads();
    }
    if (i < NN) {
        ptr[i] = s[tid] - v;
        dinv[i] = (v > 0) ? 1.0f / (float)v : 0.0f;
    }
    if (tid == 255) bsum[blockIdx.x] = s[255];
}

__global__ void scan2_k(int* __restrict__ bsum, int nb) {
    __shared__ int s[512];
    int tid = threadIdx.x;
    int v = (tid < nb) ? bsum[tid] : 0;
    s[tid] = v;
    __syncthreads();
    for (int off = 1; off < 512; off <<= 1) {
        int t = (tid >= off) ? s[tid - off] : 0;
        __syncthreads();
        s[tid] += t;
        __syncthreads();
    }
    if (tid < nb) bsum[tid] = s[tid] - v;
}

__global__ void scan3_k(int* __restrict__ ptr, const int* __restrict__ bsum) {
    int i = blockIdx.x * 256 + threadIdx.x;
    if (i < NN) ptr[i] += bsum[blockIdx.x];
    if (i == 0) ptr[NN] = NE;
}

// Phase D: fill csrc (one block per bucket; LDS cursors + LDS ptr window)
__global__ void fill_bucket_k(const int2* __restrict__ pairs, const int* __restrict__ bktPtr,
                              const int* __restrict__ ptr, int* __restrict__ csrc) {
    __shared__ int cur[256];
    __shared__ int sptr[256];
    int tid = threadIdx.x;
    int b = blockIdx.x;
    cur[tid] = 0;
    int node = (b << 8) + tid;
    sptr[tid] = (node < NN) ? ptr[node] : 0;
    __syncthreads();
    int e1 = bktPtr[b + 1];
    for (int e = bktPtr[b] + tid; e < e1; e += 256) {
        int2 pr = pairs[e];
        int lo = pr.y & 255;
        int r = atomicAdd(&cur[lo], 1);
        csrc[sptr[lo] + r] = pr.x;
    }
}

// ---------------- register-tiled fp32 GEMM (512 threads, 2x8 thread-tile) ----------------

template <int KDIM, bool INPROJ, bool HALF0>
__global__ __launch_bounds__(512) void gemm_k(const float* __restrict__ X,
                                              const float* __restrict__ WlP,
                                              const float* __restrict__ WrP,
                                              const float* __restrict__ bias,
                                              void* __restrict__ out0,
                                              float* __restrict__ out1,
                                              int dout) {
    __shared__ float xs[MT * 72];      // [m][k] row stride 72
    __shared__ float ws_[64 * 64];     // [k][n]
    const int t = threadIdx.x;
    const int mBase = blockIdx.x * MT;
    const float* W = (blockIdx.y == 0) ? WlP : WrP;
    const int ty = t >> 3;   // 0..63
    const int tx = t & 7;    // 0..7

    float acc[2][8];
    #pragma unroll
    for (int i = 0; i < 2; ++i)
        #pragma unroll
        for (int j = 0; j < 8; ++j) acc[i][j] = 0.0f;

    for (int kc = 0; kc < KDIM; kc += 64) {
        {
            int r0 = t >> 4;         // 0..31
            int c4 = t & 15;         // float4 col
            #pragma unroll
            for (int rep = 0; rep < 4; ++rep) {
                int r = r0 + rep * 32;
                int gm = mBase + r;
                float4 v = make_float4(0.f, 0.f, 0.f, 0.f);
                if (gm < NN)
                    v = *(const float4*)&X[(size_t)gm * KDIM + kc + c4 * 4];
                *(float4*)&xs[r * 72 + c4 * 4] = v;
            }
        }
        {
            int n = t >> 3;          // 0..63
            int c0 = t & 7;
            #pragma unroll
            for (int rep = 0; rep < 2; ++rep) {
                int c4 = c0 + rep * 8;   // 0..15
                float4 v = make_float4(0.f, 0.f, 0.f, 0.f);
                if (n < dout)
                    v = *(const float4*)&W[(size_t)n * KDIM + kc + c4 * 4];
                ws_[(c4 * 4 + 0) * 64 + n] = v.x;
                ws_[(c4 * 4 + 1) * 64 + n] = v.y;
                ws_[(c4 * 4 + 2) * 64 + n] = v.z;
                ws_[(c4 * 4 + 3) * 64 + n] = v.w;
            }
        }
        __syncthreads();
        #pragma unroll 4
        for (int kk = 0; kk < 16; ++kk) {
            float4 a[2];
            #pragma unroll
            for (int i = 0; i < 2; ++i)
                a[i] = *(const float4*)&xs[(ty + 64 * i) * 72 + kk * 4];
            #pragma unroll
            for (int p = 0; p < 4; ++p) {
                float4 b0 = *(const float4*)&ws_[(kk * 4 + p) * 64 + tx * 8];
                float4 b1 = *(const float4*)&ws_[(kk * 4 + p) * 64 + tx * 8 + 4];
                #pragma unroll
                for (int i = 0; i < 2; ++i) {
                    float av = (&a[i].x)[p];
                    acc[i][0] += av * b0.x;
                    acc[i][1] += av * b0.y;
                    acc[i][2] += av * b0.z;
                    acc[i][3] += av * b0.w;
                    acc[i][4] += av * b1.x;
                    acc[i][5] += av * b1.y;
                    acc[i][6] += av * b1.z;
                    acc[i][7] += av * b1.w;
                }
            }
        }
        __syncthreads();
    }

    #pragma unroll
    for (int i = 0; i < 2; ++i) {
        int m = mBase + ty + 64 * i;
        if (m >= NN) continue;
        int n0 = tx * 8;
        if (INPROJ) {
            float* o0 = (float*)out0;
            #pragma unroll
            for (int j = 0; j < 8; ++j) {
                float v = acc[i][j] + bias[n0 + j];
                o0[(size_t)m * 64 + n0 + j] = v;
                out1[(size_t)m * 64 + n0 + j] = fmaxf(v, 0.0f);
            }
        } else if (blockIdx.y == 0 && HALF0) {
            union { __half h[8]; uint4 u; } pk;
            #pragma unroll
            for (int j = 0; j < 8; ++j) pk.h[j] = __float2half(acc[i][j]);
            *(uint4*)&(((__half*)out0)[(size_t)m * 64 + n0]) = pk.u;
        } else {
            float* outp = (blockIdx.y == 0) ? (float*)out0 : out1;
            float4 v0 = make_float4(acc[i][0], acc[i][1], acc[i][2], acc[i][3]);
            float4 v1 = make_float4(acc[i][4], acc[i][5], acc[i][6], acc[i][7]);
            *(float4*)&outp[(size_t)m * 64 + n0] = v0;
            *(float4*)&outp[(size_t)m * 64 + n0 + 4] = v1;
        }
    }
}

// ---------------- gather core: 8 edges per wave, 16B loads ----------------
// Lane layout: g = lane>>3 (edge slot 0..7), c = lane&7 (feature chunk of 8).
// Per 8 edges each lane: 1 shfl + 1 uint4 (8xhalf) load; 8 lanes consume one
// full 128B row. CDNA shfl rule: ds_bpermute does NOT supply data from
// inactive lanes -> the shfl MUST be executed by all 64 lanes (wave-uniform),
// with the validity guard applied only to the USE of the result.

__device__ __forceinline__ void gather_sum8(const __half* __restrict__ ylh,
                                            const int* __restrict__ csrc,
                                            int eb, int ee, int lane,
                                            float acc[8]) {
    int g = lane >> 3;
    int c = lane & 7;
    #pragma unroll
    for (int k = 0; k < 8; ++k) acc[k] = 0.0f;
    for (int e0 = eb; e0 < ee; e0 += 64) {
        int rem = ee - e0;
        int m = rem < 64 ? rem : 64;
        int sv = (lane < m) ? csrc[e0 + lane] : 0;   // coalesced edge prefetch
        for (int j = 0; j < m; j += 8) {
            int s = __shfl(sv, j + g);   // ALL lanes execute (sources j..j+7 < 64)
            if (g < m - j) {             // guard the use, not the shfl
                union { uint4 u; __half2 h2[4]; } pk;
                pk.u = *(const uint4*)&ylh[(size_t)s * 64 + c * 8];
                #pragma unroll
                for (int q = 0; q < 4; ++q) {
                    float2 f = __half22float2(pk.h2[q]);
                    acc[2 * q]     += f.x;
                    acc[2 * q + 1] += f.y;
                }
            }
        }
    }
    // combine the 8 edge-groups (lanes with equal c): xor 8,16,32
    #pragma unroll
    for (int off = 8; off <= 32; off <<= 1)
        #pragma unroll
        for (int k = 0; k < 8; ++k)
            acc[k] += __shfl_xor(acc[k], off);
}

// ---------------- mid-layer aggregate: relu + residual ----------------

__global__ void aggregate_mid_k(const __half* __restrict__ ylh, const float* __restrict__ yr,
                                const float* __restrict__ hinp,
                                const int* __restrict__ ptr, const int* __restrict__ csrc,
                                const float* __restrict__ dinv, const float* __restrict__ bl,
                                float* __restrict__ outp) {
    int tid = threadIdx.x;
    int w = tid >> 6, lane = tid & 63;
    int i = blockIdx.x * NPB + w;
    if (i >= NN) return;
    float acc[8];
    gather_sum8(ylh, csrc, ptr[i], ptr[i + 1], lane, acc);
    int g = lane >> 3;
    int c = lane & 7;
    if (g != 0) return;                      // lanes 0..7 hold the full row
    int f0 = c * 8;
    float dv = dinv[i];
    float4 yr0 = *(const float4*)&yr[(size_t)i * 64 + f0];
    float4 yr1 = *(const float4*)&yr[(size_t)i * 64 + f0 + 4];
    float4 bl0 = *(const float4*)&bl[f0];
    float4 bl1 = *(const float4*)&bl[f0 + 4];
    float4 h0 = *(const float4*)&hinp[(size_t)i * 64 + f0];
    float4 h1 = *(const float4*)&hinp[(size_t)i * 64 + f0 + 4];
    float4 r0, r1;
    r0.x = fmaxf(acc[0] * dv + yr0.x + bl0.x, 0.0f) + 0.2f * h0.x;
    r0.y = fmaxf(acc[1] * dv + yr0.y + bl0.y, 0.0f) + 0.2f * h0.y;
    r0.z = fmaxf(acc[2] * dv + yr0.z + bl0.z, 0.0f) + 0.2f * h0.z;
    r0.w = fmaxf(acc[3] * dv + yr0.w + bl0.w, 0.0f) + 0.2f * h0.w;
    r1.x = fmaxf(acc[4] * dv + yr1.x + bl1.x, 0.0f) + 0.2f * h1.x;
    r1.y = fmaxf(acc[5] * dv + yr1.y + bl1.y, 0.0f) + 0.2f * h1.y;
    r1.z = fmaxf(acc[6] * dv + yr1.z + bl1.z, 0.0f) + 0.2f * h1.z;
    r1.w = fmaxf(acc[7] * dv + yr1.w + bl1.w, 0.0f) + 0.2f * h1.w;
    *(float4*)&outp[(size_t)i * 64 + f0] = r0;
    *(float4*)&outp[(size_t)i * 64 + f0 + 4] = r1;
}

// ---------------- final aggregate fused with log_softmax ----------------

__global__ void aggregate_final_k(const __half* __restrict__ ylh, const float* __restrict__ yr,
                                  const int* __restrict__ ptr, const int* __restrict__ csrc,
                                  const float* __restrict__ dinv, const float* __restrict__ bl,
                                  float* __restrict__ outp) {
    int tid = threadIdx.x;
    int w = tid >> 6, lane = tid & 63;
    int i = blockIdx.x * NPB + w;
    if (i >= NN) return;
    float acc[8];
    gather_sum8(ylh, csrc, ptr[i], ptr[i + 1], lane, acc);
    int g = lane >> 3;
    int c = lane & 7;
    int f0 = c * 8;
    float dv = dinv[i];
    float v[8];
    #pragma unroll
    for (int k = 0; k < 8; ++k) {
        int f = f0 + k;
        v[k] = (f < DOUT_FINAL) ? acc[k] * dv + yr[(size_t)i * 64 + f] + bl[f]
                                : -__builtin_inff();
    }
    // row max: in-lane over 8, then across c (xor 1,2,4 within the 8-lane group)
    float mx = v[0];
    #pragma unroll
    for (int k = 1; k < 8; ++k) mx = fmaxf(mx, v[k]);
    #pragma unroll
    for (int off = 1; off <= 4; off <<= 1) mx = fmaxf(mx, __shfl_xor(mx, off));
    float ex = 0.0f;
    #pragma unroll
    for (int k = 0; k < 8; ++k)
        if (f0 + k < DOUT_FINAL) ex += expf(v[k] - mx);
    #pragma unroll
    for (int off = 1; off <= 4; off <<= 1) ex += __shfl_xor(ex, off);
    float ls = logf(ex);
    if (g == 0) {
        #pragma unroll
        for (int k = 0; k < 8; ++k) {
            int f = f0 + k;
            if (f < DOUT_FINAL)
                outp[(size_t)i * DOUT_FINAL + f] = v[k] - mx - ls;
        }
    }
}

// ---------------- launch ----------------

extern "C" void kernel_launch(void* const* d_in, const int* in_sizes, int n_in,
                              void* d_out, int out_size, void* d_ws, size_t ws_size,
                              hipStream_t stream) {
    const float* x    = (const float*)d_in[0];
    const int*   ei   = (const int*)d_in[1];
    const float* Win  = (const float*)d_in[2];
    const float* bin  = (const float*)d_in[3];
    const float* Wl0  = (const float*)d_in[4];
    const float* Wr0  = (const float*)d_in[5];
    const float* bl0  = (const float*)d_in[6];
    const float* Wl1  = (const float*)d_in[7];
    const float* Wr1  = (const float*)d_in[8];
    const float* bl1  = (const float*)d_in[9];
    const float* Wl2  = (const float*)d_in[10];
    const float* Wr2  = (const float*)d_in[11];
    const float* bl2  = (const float*)d_in[12];
    const float* Wl3  = (const float*)d_in[13];
    const float* Wr3  = (const float*)d_in[14];
    const float* bl3  = (const float*)d_in[15];
    float* out = (float*)d_out;

    const int* src = ei;
    const int* dst = ei + NE;

    size_t off = 0;
    auto alloc = [&](size_t bytes) -> void* {
        void* p = (char*)d_ws + off;
        off += (bytes + 255) & ~(size_t)255;
        return p;
    };
    int*    bkt  = (int*)alloc((size_t)2 * NBKT * 4);   // [bktCnt | bktCur]
    int*    bktPtr = (int*)alloc((size_t)(NBKT + 1) * 4);
    int2*   pairs  = (int2*)alloc((size_t)NE * 8);
    int*    cnt  = (int*)alloc((size_t)NN * 4);
    int*    ptr  = (int*)alloc((size_t)(NN + 1) * 4);
    float*  dinv = (float*)alloc((size_t)NN * 4);
    int*    csrc = (int*)alloc((size_t)NE * 4);
    int*    bsum = (int*)alloc(512 * 4);
    float*  hinp = (float*)alloc((size_t)NN * 64 * 4);
    float*  xa   = (float*)alloc((size_t)NN * 64 * 4);
    float*  xb   = (float*)alloc((size_t)NN * 64 * 4);
    __half* ylh  = (__half*)alloc((size_t)NN * 64 * 2);
    float*  yr   = (float*)alloc((size_t)NN * 64 * 4);
    int*    bktCnt = bkt;
    int*    bktCur = bkt + NBKT;

    const int NB_NODE = (NN + 255) / 256;             // 391
    const int NB_WAVE = (NN + NPB - 1) / NPB;         // 25000
    const int NB_GEMM = (NN + MT - 1) / MT;           // 782
    const int NB_SCAT = (NE + EB - 1) / EB;           // 293

    // ---- binned CSR build ----
    hipMemsetAsync(bkt, 0, (size_t)2 * NBKT * 4, stream);
    bucket_hist_k<<<512, 256, 0, stream>>>(dst, bktCnt);
    bscan_k<<<1, 512, 0, stream>>>(bktCnt, bktPtr);
    scatter_pairs_k<<<NB_SCAT, 256, 0, stream>>>(src, dst, bktPtr, bktCur, pairs);
    count_node_k<<<NBKT, 256, 0, stream>>>(pairs, bktPtr, cnt);
    scan1_k<<<NB_NODE, 256, 0, stream>>>(cnt, ptr, bsum, dinv);
    scan2_k<<<1, 512, 0, stream>>>(bsum, NB_NODE);
    scan3_k<<<NB_NODE, 256, 0, stream>>>(ptr, bsum);
    fill_bucket_k<<<NBKT, 256, 0, stream>>>(pairs, bktPtr, ptr, csrc);

    // ---- input projection: hinp = x@Win^T + bin ; xa = relu(hinp) ----
    gemm_k<128, true, false><<<dim3(NB_GEMM, 1), 512, 0, stream>>>(x, Win, Win, bin, hinp, xa, 64);

    // layer 0: xa -> xb
    gemm_k<64, false, true><<<dim3(NB_GEMM, 2), 512, 0, stream>>>(xa, Wl0, Wr0, nullptr, ylh, yr, 64);
    aggregate_mid_k<<<NB_WAVE, 256, 0, stream>>>(ylh, yr, hinp, ptr, csrc, dinv, bl0, xb);
    // layer 1: xb -> xa
    gemm_k<64, false, true><<<dim3(NB_GEMM, 2), 512, 0, stream>>>(xb, Wl1, Wr1, nullptr, ylh, yr, 64);
    aggregate_mid_k<<<NB_WAVE, 256, 0, stream>>>(ylh, yr, hinp, ptr, csrc, dinv, bl1, xa);
    // layer 2: xa -> xb
    gemm_k<64, false, true><<<dim3(NB_GEMM, 2), 512, 0, stream>>>(xa, Wl2, Wr2, nullptr, ylh, yr, 64);
    aggregate_mid_k<<<NB_WAVE, 256, 0, stream>>>(ylh, yr, hinp, ptr, csrc, dinv, bl2, xb);
    // layer 3: xb -> out (fused log_softmax)
    gemm_k<64, false, true><<<dim3(NB_GEMM, 2), 512, 0, stream>>>(xb, Wl3, Wr3, nullptr, ylh, yr, 47);
    aggregate_final_k<<<NB_WAVE, 256, 0, stream>>>(ylh, yr, ptr, csrc, dinv, bl3, out);
}

// Round 15
// 410.867 us; speedup vs baseline: 1.1206x; 1.1206x over previous
//
#include <hip/hip_runtime.h>
#include <hip/hip_fp16.h>

#define NN 100000
#define NE 1200000
#define DIN 128
#define DH 64
#define DOUT_FINAL 47
#define NPB 4        // nodes per block in gather kernels
#define MT 128       // GEMM m-tile
#define NBKT 391     // (NN + 255) >> 8  — bucket = dst >> 8 (256 nodes/bucket)
#define EB 4096      // edges per block in scatter_pairs_k

// ---------------- binned CSR build ----------------

// Phase A: global bucket histogram (LDS-privatized)
__global__ void bucket_hist_k(const int* __restrict__ dst, int* __restrict__ bktCnt) {
    __shared__ int h[NBKT];
    int tid = threadIdx.x;
    for (int i = tid; i < NBKT; i += 256) h[i] = 0;
    __syncthreads();
    for (int e = blockIdx.x * 256 + tid; e < NE; e += gridDim.x * 256)
        atomicAdd(&h[dst[e] >> 8], 1);
    __syncthreads();
    for (int i = tid; i < NBKT; i += 256)
        if (h[i]) atomicAdd(&bktCnt[i], h[i]);
}

// Phase A2: exclusive scan of bucket counts (single block)
__global__ void bscan_k(const int* __restrict__ bktCnt, int* __restrict__ bktPtr) {
    __shared__ int s[512];
    int tid = threadIdx.x;
    int v = (tid < NBKT) ? bktCnt[tid] : 0;
    s[tid] = v;
    __syncthreads();
    for (int off = 1; off < 512; off <<= 1) {
        int t = (tid >= off) ? s[tid - off] : 0;
        __syncthreads();
        s[tid] += t;
        __syncthreads();
    }
    if (tid < NBKT) bktPtr[tid] = s[tid] - v;
    if (tid == 0) bktPtr[NBKT] = NE;
}

// Phase B: scatter (src,dst) pairs into bucket-contiguous order.
__global__ void scatter_pairs_k(const int* __restrict__ src, const int* __restrict__ dst,
                                const int* __restrict__ bktPtr, int* __restrict__ bktCur,
                                int2* __restrict__ pairs) {
    __shared__ int h[NBKT];
    __shared__ int base[NBKT];
    __shared__ int cur[NBKT];
    int tid = threadIdx.x;
    int e0 = blockIdx.x * EB;
    int e1 = e0 + EB < NE ? e0 + EB : NE;
    for (int i = tid; i < NBKT; i += 256) { h[i] = 0; cur[i] = 0; }
    __syncthreads();
    for (int e = e0 + tid; e < e1; e += 256)
        atomicAdd(&h[dst[e] >> 8], 1);
    __syncthreads();
    for (int i = tid; i < NBKT; i += 256) {
        int c = h[i];
        base[i] = bktPtr[i] + (c ? atomicAdd(&bktCur[i], c) : 0);
    }
    __syncthreads();
    for (int e = e0 + tid; e < e1; e += 256) {
        int d = dst[e];
        int b = d >> 8;
        int p = base[b] + atomicAdd(&cur[b], 1);
        pairs[p] = make_int2(src[e], d);
    }
}

// Phase C: per-node degree via LDS-only atomics (one block per bucket)
__global__ void count_node_k(const int2* __restrict__ pairs, const int* __restrict__ bktPtr,
                             int* __restrict__ cnt) {
    __shared__ int h[256];
    int tid = threadIdx.x;
    int b = blockIdx.x;
    h[tid] = 0;
    __syncthreads();
    int e1 = bktPtr[b + 1];
    for (int e = bktPtr[b] + tid; e < e1; e += 256)
        atomicAdd(&h[pairs[e].y & 255], 1);
    __syncthreads();
    int node = (b << 8) + tid;
    if (node < NN) cnt[node] = h[tid];
}

// node-level exclusive scan (3 kernels)
__global__ void scan1_k(const int* __restrict__ cnt, int* __restrict__ ptr,
                        int* __restrict__ bsum, float* __restrict__ dinv) {
    __shared__ int s[256];
    int tid = threadIdx.x;
    int i = blockIdx.x * 256 + tid;
    int v = (i < NN) ? cnt[i] : 0;
    s[tid] = v;
    __syncthreads();
    for (int off = 1; off < 256; off <<= 1) {
        int t = (tid >= off) ? s[tid - off] : 0;
        __syncthreads();
        s[tid] += t;
        __syncthreads();
    }
    if (i < NN) {
        ptr[i] = s[tid] - v;
        dinv[i] = (v > 0) ? 1.0f / (float)v : 0.0f;
    }
    if (tid == 255) bsum[blockIdx.x] = s[255];
}

__global__ void scan2_k(int* __restrict__ bsum, int nb) {
    __shared__ int s[512];
    int tid = threadIdx.x;
    int v = (tid < nb) ? bsum[tid] : 0;
    s[tid] = v;
    __syncthreads();
    for (int off = 1; off < 512; off <<= 1) {
        int t = (tid >= off) ? s[tid - off] : 0;
        __syncthreads();
        s[tid] += t;
        __syncthreads();
    }
    if (tid < nb) bsum[tid] = s[tid] - v;
}

__global__ void scan3_k(int* __restrict__ ptr, const int* __restrict__ bsum) {
    int i = blockIdx.x * 256 + threadIdx.x;
    if (i < NN) ptr[i] += bsum[blockIdx.x];
    if (i == 0) ptr[NN] = NE;
}

// Phase D: fill csrc (one block per bucket; LDS cursors + LDS ptr window)
__global__ void fill_bucket_k(const int2* __restrict__ pairs, const int* __restrict__ bktPtr,
                              const int* __restrict__ ptr, int* __restrict__ csrc) {
    __shared__ int cur[256];
    __shared__ int sptr[256];
    int tid = threadIdx.x;
    int b = blockIdx.x;
    cur[tid] = 0;
    int node = (b << 8) + tid;
    sptr[tid] = (node < NN) ? ptr[node] : 0;
    __syncthreads();
    int e1 = bktPtr[b + 1];
    for (int e = bktPtr[b] + tid; e < e1; e += 256) {
        int2 pr = pairs[e];
        int lo = pr.y & 255;
        int r = atomicAdd(&cur[lo], 1);
        csrc[sptr[lo] + r] = pr.x;
    }
}

// ---------------- register-tiled fp32 GEMM (512 threads, 2x8 thread-tile) ----------------

template <int KDIM, bool INPROJ, bool HALF0>
__global__ __launch_bounds__(512) void gemm_k(const float* __restrict__ X,
                                              const float* __restrict__ WlP,
                                              const float* __restrict__ WrP,
                                              const float* __restrict__ bias,
                                              void* __restrict__ out0,
                                              float* __restrict__ out1,
                                              int dout) {
    __shared__ float xs[MT * 72];      // [m][k] row stride 72
    __shared__ float ws_[64 * 64];     // [k][n]
    const int t = threadIdx.x;
    const int mBase = blockIdx.x * MT;
    const float* W = (blockIdx.y == 0) ? WlP : WrP;
    const int ty = t >> 3;   // 0..63
    const int tx = t & 7;    // 0..7

    float acc[2][8];
    #pragma unroll
    for (int i = 0; i < 2; ++i)
        #pragma unroll
        for (int j = 0; j < 8; ++j) acc[i][j] = 0.0f;

    for (int kc = 0; kc < KDIM; kc += 64) {
        {
            int r0 = t >> 4;         // 0..31
            int c4 = t & 15;         // float4 col
            #pragma unroll
            for (int rep = 0; rep < 4; ++rep) {
                int r = r0 + rep * 32;
                int gm = mBase + r;
                float4 v = make_float4(0.f, 0.f, 0.f, 0.f);
                if (gm < NN)
                    v = *(const float4*)&X[(size_t)gm * KDIM + kc + c4 * 4];
                *(float4*)&xs[r * 72 + c4 * 4] = v;
            }
        }
        {
            int n = t >> 3;          // 0..63
            int c0 = t & 7;
            #pragma unroll
            for (int rep = 0; rep < 2; ++rep) {
                int c4 = c0 + rep * 8;   // 0..15
                float4 v = make_float4(0.f, 0.f, 0.f, 0.f);
                if (n < dout)
                    v = *(const float4*)&W[(size_t)n * KDIM + kc + c4 * 4];
                ws_[(c4 * 4 + 0) * 64 + n] = v.x;
                ws_[(c4 * 4 + 1) * 64 + n] = v.y;
                ws_[(c4 * 4 + 2) * 64 + n] = v.z;
                ws_[(c4 * 4 + 3) * 64 + n] = v.w;
            }
        }
        __syncthreads();
        #pragma unroll 4
        for (int kk = 0; kk < 16; ++kk) {
            float4 a[2];
            #pragma unroll
            for (int i = 0; i < 2; ++i)
                a[i] = *(const float4*)&xs[(ty + 64 * i) * 72 + kk * 4];
            #pragma unroll
            for (int p = 0; p < 4; ++p) {
                float4 b0 = *(const float4*)&ws_[(kk * 4 + p) * 64 + tx * 8];
                float4 b1 = *(const float4*)&ws_[(kk * 4 + p) * 64 + tx * 8 + 4];
                #pragma unroll
                for (int i = 0; i < 2; ++i) {
                    float av = (&a[i].x)[p];
                    acc[i][0] += av * b0.x;
                    acc[i][1] += av * b0.y;
                    acc[i][2] += av * b0.z;
                    acc[i][3] += av * b0.w;
                    acc[i][4] += av * b1.x;
                    acc[i][5] += av * b1.y;
                    acc[i][6] += av * b1.z;
                    acc[i][7] += av * b1.w;
                }
            }
        }
        __syncthreads();
    }

    #pragma unroll
    for (int i = 0; i < 2; ++i) {
        int m = mBase + ty + 64 * i;
        if (m >= NN) continue;
        int n0 = tx * 8;
        if (INPROJ) {
            float* o0 = (float*)out0;
            #pragma unroll
            for (int j = 0; j < 8; ++j) {
                float v = acc[i][j] + bias[n0 + j];
                o0[(size_t)m * 64 + n0 + j] = v;
                out1[(size_t)m * 64 + n0 + j] = fmaxf(v, 0.0f);
            }
        } else if (blockIdx.y == 0 && HALF0) {
            union { __half h[8]; uint4 u; } pk;
            #pragma unroll
            for (int j = 0; j < 8; ++j) pk.h[j] = __float2half(acc[i][j]);
            *(uint4*)&(((__half*)out0)[(size_t)m * 64 + n0]) = pk.u;
        } else {
            float* outp = (blockIdx.y == 0) ? (float*)out0 : out1;
            float4 v0 = make_float4(acc[i][0], acc[i][1], acc[i][2], acc[i][3]);
            float4 v1 = make_float4(acc[i][4], acc[i][5], acc[i][6], acc[i][7]);
            *(float4*)&outp[(size_t)m * 64 + n0] = v0;
            *(float4*)&outp[(size_t)m * 64 + n0 + 4] = v1;
        }
    }
}

// ---------------- gather core: 2 edges per wave, half2 loads (round-12 proven) ----------------
// Lane layout: half = lane>>5, fl = lane&31. Lane handles features {2fl, 2fl+1}.
// 4 independent loads in flight per lane (MLP is the lever — round-14 lesson).
// Addresses computed as 32-bit byte offsets off a char* base: s*128 + fl*4
// (one v_mad) -> compiler can emit saddr-form global_load.

__device__ __forceinline__ float2 gather_sum2(const __half* __restrict__ ylh,
                                              const int* __restrict__ csrc,
                                              int eb, int ee, int lane) {
    int half = lane >> 5;
    int fo = (lane & 31) * 4;                // byte offset of this lane's half2
    const char* base = (const char*)ylh;
    float accx = 0.0f, accy = 0.0f;
    for (int e0 = eb; e0 < ee; e0 += 64) {
        int rem = ee - e0;
        int m = rem < 64 ? rem : 64;
        int sv = (lane < m) ? csrc[e0 + lane] : 0;   // coalesced edge prefetch
        int j = 0;
        for (; j + 8 <= m; j += 8) {
            int sA = __shfl(sv, j + 0 + half);
            int sB = __shfl(sv, j + 2 + half);
            int sC = __shfl(sv, j + 4 + half);
            int sD = __shfl(sv, j + 6 + half);
            float2 a = __half22float2(*(const __half2*)(base + (sA * 128 + fo)));
            float2 b = __half22float2(*(const __half2*)(base + (sB * 128 + fo)));
            float2 c = __half22float2(*(const __half2*)(base + (sC * 128 + fo)));
            float2 d = __half22float2(*(const __half2*)(base + (sD * 128 + fo)));
            accx += (a.x + b.x) + (c.x + d.x);
            accy += (a.y + b.y) + (c.y + d.y);
        }
        for (; j + 2 <= m; j += 2) {
            int s = __shfl(sv, j + half);
            float2 a = __half22float2(*(const __half2*)(base + (s * 128 + fo)));
            accx += a.x;
            accy += a.y;
        }
        if (j < m) {                       // odd tail: half 0 only
            int s = __shfl(sv, j);
            if (half == 0) {
                float2 a = __half22float2(*(const __half2*)(base + (s * 128 + fo)));
                accx += a.x;
                accy += a.y;
            }
        }
    }
    accx += __shfl_xor(accx, 32);
    accy += __shfl_xor(accy, 32);
    return make_float2(accx, accy);        // duplicated across halves
}

// ---------------- mid-layer aggregate: relu + residual ----------------

__global__ void aggregate_mid_k(const __half* __restrict__ ylh, const float* __restrict__ yr,
                                const float* __restrict__ hinp,
                                const int* __restrict__ ptr, const int* __restrict__ csrc,
                                const float* __restrict__ dinv, const float* __restrict__ bl,
                                float* __restrict__ outp) {
    int tid = threadIdx.x;
    int w = tid >> 6, lane = tid & 63;
    int i = blockIdx.x * NPB + w;
    if (i >= NN) return;
    float2 acc = gather_sum2(ylh, csrc, ptr[i], ptr[i + 1], lane);
    int half = lane >> 5;
    int f0 = (lane & 31) * 2;
    float dv = dinv[i];
    float2 yrv = *(const float2*)&yr[(size_t)i * 64 + f0];
    float2 blv = *(const float2*)&bl[f0];
    float2 hv = *(const float2*)&hinp[(size_t)i * 64 + f0];
    float2 r;
    r.x = fmaxf(acc.x * dv + yrv.x + blv.x, 0.0f) + 0.2f * hv.x;
    r.y = fmaxf(acc.y * dv + yrv.y + blv.y, 0.0f) + 0.2f * hv.y;
    if (half == 0) *(float2*)&outp[(size_t)i * 64 + f0] = r;
}

// ---------------- final aggregate fused with log_softmax ----------------

__global__ void aggregate_final_k(const __half* __restrict__ ylh, const float* __restrict__ yr,
                                  const int* __restrict__ ptr, const int* __restrict__ csrc,
                                  const float* __restrict__ dinv, const float* __restrict__ bl,
                                  float* __restrict__ outp) {
    int tid = threadIdx.x;
    int w = tid >> 6, lane = tid & 63;
    int i = blockIdx.x * NPB + w;
    if (i >= NN) return;
    float2 acc = gather_sum2(ylh, csrc, ptr[i], ptr[i + 1], lane);
    int half = lane >> 5;
    int f0 = (lane & 31) * 2;
    float dv = dinv[i];
    float2 yrv = *(const float2*)&yr[(size_t)i * 64 + f0];
    float b0 = (f0 < DOUT_FINAL) ? bl[f0] : 0.0f;
    float b1 = (f0 + 1 < DOUT_FINAL) ? bl[f0 + 1] : 0.0f;
    float vx = (f0 < DOUT_FINAL) ? acc.x * dv + yrv.x + b0 : -__builtin_inff();
    float vy = (f0 + 1 < DOUT_FINAL) ? acc.y * dv + yrv.y + b1 : -__builtin_inff();
    // width-32 reductions (halves hold duplicates; masks <=16 stay in-group)
    float mx = fmaxf(vx, vy);
    for (int o = 16; o; o >>= 1) mx = fmaxf(mx, __shfl_xor(mx, o));
    float ex = ((f0 < DOUT_FINAL) ? expf(vx - mx) : 0.0f) +
               ((f0 + 1 < DOUT_FINAL) ? expf(vy - mx) : 0.0f);
    float s = ex;
    for (int o = 16; o; o >>= 1) s += __shfl_xor(s, o);
    float ls = logf(s);
    if (half == 0) {
        if (f0 < DOUT_FINAL)     outp[(size_t)i * DOUT_FINAL + f0] = vx - mx - ls;
        if (f0 + 1 < DOUT_FINAL) outp[(size_t)i * DOUT_FINAL + f0 + 1] = vy - mx - ls;
    }
}

// ---------------- launch ----------------

extern "C" void kernel_launch(void* const* d_in, const int* in_sizes, int n_in,
                              void* d_out, int out_size, void* d_ws, size_t ws_size,
                              hipStream_t stream) {
    const float* x    = (const float*)d_in[0];
    const int*   ei   = (const int*)d_in[1];
    const float* Win  = (const float*)d_in[2];
    const float* bin  = (const float*)d_in[3];
    const float* Wl0  = (const float*)d_in[4];
    const float* Wr0  = (const float*)d_in[5];
    const float* bl0  = (const float*)d_in[6];
    const float* Wl1  = (const float*)d_in[7];
    const float* Wr1  = (const float*)d_in[8];
    const float* bl1  = (const float*)d_in[9];
    const float* Wl2  = (const float*)d_in[10];
    const float* Wr2  = (const float*)d_in[11];
    const float* bl2  = (const float*)d_in[12];
    const float* Wl3  = (const float*)d_in[13];
    const float* Wr3  = (const float*)d_in[14];
    const float* bl3  = (const float*)d_in[15];
    float* out = (float*)d_out;

    const int* src = ei;
    const int* dst = ei + NE;

    size_t off = 0;
    auto alloc = [&](size_t bytes) -> void* {
        void* p = (char*)d_ws + off;
        off += (bytes + 255) & ~(size_t)255;
        return p;
    };
    int*    bkt  = (int*)alloc((size_t)2 * NBKT * 4);   // [bktCnt | bktCur]
    int*    bktPtr = (int*)alloc((size_t)(NBKT + 1) * 4);
    int2*   pairs  = (int2*)alloc((size_t)NE * 8);
    int*    cnt  = (int*)alloc((size_t)NN * 4);
    int*    ptr  = (int*)alloc((size_t)(NN + 1) * 4);
    float*  dinv = (float*)alloc((size_t)NN * 4);
    int*    csrc = (int*)alloc((size_t)NE * 4);
    int*    bsum = (int*)alloc(512 * 4);
    float*  hinp = (float*)alloc((size_t)NN * 64 * 4);
    float*  xa   = (float*)alloc((size_t)NN * 64 * 4);
    float*  xb   = (float*)alloc((size_t)NN * 64 * 4);
    __half* ylh  = (__half*)alloc((size_t)NN * 64 * 2);
    float*  yr   = (float*)alloc((size_t)NN * 64 * 4);
    int*    bktCnt = bkt;
    int*    bktCur = bkt + NBKT;

    const int NB_NODE = (NN + 255) / 256;             // 391
    const int NB_WAVE = (NN + NPB - 1) / NPB;         // 25000
    const int NB_GEMM = (NN + MT - 1) / MT;           // 782
    const int NB_SCAT = (NE + EB - 1) / EB;           // 293

    // ---- binned CSR build ----
    hipMemsetAsync(bkt, 0, (size_t)2 * NBKT * 4, stream);
    bucket_hist_k<<<512, 256, 0, stream>>>(dst, bktCnt);
    bscan_k<<<1, 512, 0, stream>>>(bktCnt, bktPtr);
    scatter_pairs_k<<<NB_SCAT, 256, 0, stream>>>(src, dst, bktPtr, bktCur, pairs);
    count_node_k<<<NBKT, 256, 0, stream>>>(pairs, bktPtr, cnt);
    scan1_k<<<NB_NODE, 256, 0, stream>>>(cnt, ptr, bsum, dinv);
    scan2_k<<<1, 512, 0, stream>>>(bsum, NB_NODE);
    scan3_k<<<NB_NODE, 256, 0, stream>>>(ptr, bsum);
    fill_bucket_k<<<NBKT, 256, 0, stream>>>(pairs, bktPtr, ptr, csrc);

    // ---- input projection: hinp = x@Win^T + bin ; xa = relu(hinp) ----
    gemm_k<128, true, false><<<dim3(NB_GEMM, 1), 512, 0, stream>>>(x, Win, Win, bin, hinp, xa, 64);

    // layer 0: xa -> xb
    gemm_k<64, false, true><<<dim3(NB_GEMM, 2), 512, 0, stream>>>(xa, Wl0, Wr0, nullptr, ylh, yr, 64);
    aggregate_mid_k<<<NB_WAVE, 256, 0, stream>>>(ylh, yr, hinp, ptr, csrc, dinv, bl0, xb);
    // layer 1: xb -> xa
    gemm_k<64, false, true><<<dim3(NB_GEMM, 2), 512, 0, stream>>>(xb, Wl1, Wr1, nullptr, ylh, yr, 64);
    aggregate_mid_k<<<NB_WAVE, 256, 0, stream>>>(ylh, yr, hinp, ptr, csrc, dinv, bl1, xa);
    // layer 2: xa -> xb
    gemm_k<64, false, true><<<dim3(NB_GEMM, 2), 512, 0, stream>>>(xa, Wl2, Wr2, nullptr, ylh, yr, 64);
    aggregate_mid_k<<<NB_WAVE, 256, 0, stream>>>(ylh, yr, hinp, ptr, csrc, dinv, bl2, xb);
    // layer 3: xb -> out (fused log_softmax)
    gemm_k<64, false, true><<<dim3(NB_GEMM, 2), 512, 0, stream>>>(xb, Wl3, Wr3, nullptr, ylh, yr, 47);
    aggregate_final_k<<<NB_WAVE, 256, 0, stream>>>(ylh, yr, ptr, csrc, dinv, bl3, out);
}